// Round 9
// baseline (186.778 us; speedup 1.0000x reference)
//
#include <hip/hip_runtime.h>
#include <math.h>

typedef short short8 __attribute__((ext_vector_type(8)));
typedef float f32x4 __attribute__((ext_vector_type(4)));
typedef unsigned int u32x2 __attribute__((ext_vector_type(2)));

typedef __attribute__((address_space(1))) const void* as1p;
typedef __attribute__((address_space(3))) void* as3p;

__device__ __forceinline__ unsigned short f2bf(float f) {
    unsigned int u = __float_as_uint(f);
    u += 0x7fffu + ((u >> 16) & 1u);          // RNE; inputs finite
    return (unsigned short)(u >> 16);
}

// ---------------------------------------------------------------------------
// fp32 -> bf16 conversion of x, W_qkv, W_o in one launch (4 elems/thread)
// ---------------------------------------------------------------------------
__global__ void cvt_all_bf16(const float* __restrict__ x,
                             const float* __restrict__ wqkv,
                             const float* __restrict__ wo,
                             unsigned short* __restrict__ xb,
                             unsigned short* __restrict__ wqkvb,
                             unsigned short* __restrict__ wob) {
    int i = blockIdx.x * blockDim.x + threadIdx.x;   // [0, 2097152)
    const float* src;
    unsigned short* dst;
    int off;
    if (i < 1048576)       { src = x;    dst = xb;    off = i; }
    else if (i < 1835008)  { src = wqkv; dst = wqkvb; off = i - 1048576; }
    else                   { src = wo;   dst = wob;   off = i - 1835008; }
    float4 v = ((const float4*)src)[off];
    ushort4 o = make_ushort4(f2bf(v.x), f2bf(v.y), f2bf(v.z), f2bf(v.w));
    ((ushort4*)dst)[off] = o;
}

// ---------------------------------------------------------------------------
// MFMA NT GEMM: C[m,n] = sum_k A[m,k]*B[n,k]. Block tile BM x 128 (BM=RF*32),
// BK=32, 4 waves (2x2), global_load_lds width-16 staging, 2-barrier K-loop.
// LDS bank-conflict fix via global-source XOR swizzle. XCD-swizzled flat
// grid. DO_ROPE: fused RoPE on the fp32 accumulator before store.
// r9: gemm2 upgraded RF 2->4 (BM 64->128): doubles per-wave MFMA density and
// B-panel reuse; grid 256 = 32 mt x 8 nt, 1 block/CU, NTX=1 (xcd owns its
// n-tile column; B panel 256 KB L2-resident).
// ---------------------------------------------------------------------------
template <int RF, int NTX, bool BF16_OUT, bool DO_ROPE>
__global__ __launch_bounds__(256) void gemm_nt_mfma(
    const unsigned short* __restrict__ A, const unsigned short* __restrict__ B,
    void* __restrict__ Cv, const int* __restrict__ pos, int N, int K) {
    constexpr int BM = RF * 32;
    __shared__ unsigned short As[BM * 32];
    __shared__ unsigned short Bs[128 * 32];
    const int tid = threadIdx.x;
    const int wave = tid >> 6, lane = tid & 63;
    const int L = blockIdx.x;
    const int xcd = L & 7, idx = L >> 3;
    const int nt_ = xcd * NTX + idx % NTX;
    const int mt  = idx / NTX;
    const int m0 = mt * BM, n0 = nt_ << 7;
    const int wr = ((wave >> 1) & 1) * (RF * 16);
    const int wc = (wave & 1) << 6;

    const int r0 = tid >> 2;
    const int ko = (((tid & 3) ^ ((r0 >> 1) & 3)) << 3);
    const unsigned short* Ap0 = A + (size_t)(m0 + r0) * K + ko;
    const unsigned short* Ap1 = A + (size_t)(m0 + (RF == 4 ? 64 : 0) + r0) * K + ko;
    const unsigned short* Bp0 = B + (size_t)(n0 + r0) * K + ko;
    const unsigned short* Bp1 = B + (size_t)(n0 + 64 + r0) * K + ko;

    f32x4 acc[RF][4] = {};
    const int lro = lane & 15;
    const int cs = ((lane >> 4) ^ ((lro >> 1) & 3)) << 3;  // physical chunk (shorts)

    for (int k0 = 0; k0 < K; k0 += 32) {
        __syncthreads();
        __builtin_amdgcn_global_load_lds((as1p)(Ap0 + k0), (as3p)(As + tid * 8), 16, 0, 0);
        if constexpr (RF == 4)
            __builtin_amdgcn_global_load_lds((as1p)(Ap1 + k0), (as3p)(As + (256 + tid) * 8), 16, 0, 0);
        __builtin_amdgcn_global_load_lds((as1p)(Bp0 + k0), (as3p)(Bs + tid * 8), 16, 0, 0);
        __builtin_amdgcn_global_load_lds((as1p)(Bp1 + k0), (as3p)(Bs + (256 + tid) * 8), 16, 0, 0);
        __syncthreads();

        short8 af[RF], bfr[4];
        #pragma unroll
        for (int i = 0; i < RF; i++) af[i] = *(const short8*)&As[(wr + i * 16 + lro) * 32 + cs];
        #pragma unroll
        for (int j = 0; j < 4; j++) bfr[j] = *(const short8*)&Bs[(wc + j * 16 + lro) * 32 + cs];
        #pragma unroll
        for (int i = 0; i < RF; i++)
            #pragma unroll
            for (int j = 0; j < 4; j++)
                acc[i][j] = __builtin_amdgcn_mfma_f32_16x16x32_bf16(af[i], bfr[j], acc[i][j], 0, 0, 0);
    }

    const int row_b = m0 + wr + ((lane >> 4) << 2);
    const int col_b = n0 + wc + lro;

    if constexpr (DO_ROPE) {
        const int sec = (n0 + wc) >> 10;           // 0=q, 1=k, 2=v
        if (sec < 2) {
            const float qs = (sec == 0) ? 0.18033688011112042f : 1.0f;  // 1/8*log2e
            const float sgn = (lane & 1) ? 1.0f : -1.0f;
            float ps[RF * 4];
            #pragma unroll
            for (int i = 0; i < RF; i++)
                #pragma unroll
                for (int r = 0; r < 4; r++)
                    ps[i * 4 + r] = (float)pos[(row_b + i * 16 + r) & 2047];
            #pragma unroll
            for (int j = 0; j < 4; j++) {
                float invf_rev = exp2f(-(float)((lro >> 1) + 8 * j) * 0.41524101186092029f)
                                 * 0.15915494309189535f;
                #pragma unroll
                for (int i = 0; i < RF; i++)
                    #pragma unroll
                    for (int r = 0; r < 4; r++) {
                        float rev = ps[i * 4 + r] * invf_rev;
                        rev -= floorf(rev);
                        float c = __builtin_amdgcn_cosf(rev) * qs;
                        float s = __builtin_amdgcn_sinf(rev) * (qs * sgn);
                        float mine = acc[i][j][r];
                        float partner = __shfl_xor(mine, 1, 64);
                        acc[i][j][r] = mine * c + partner * s;
                    }
            }
        }
    }

    #pragma unroll
    for (int i = 0; i < RF; i++)
        #pragma unroll
        for (int j = 0; j < 4; j++)
            #pragma unroll
            for (int r = 0; r < 4; r++) {
                size_t idx2 = (size_t)(row_b + i * 16 + r) * N + (col_b + j * 16);
                if constexpr (BF16_OUT) ((unsigned short*)Cv)[idx2] = f2bf(acc[i][j][r]);
                else ((float*)Cv)[idx2] = acc[i][j][r];
            }
}

// ---------------------------------------------------------------------------
// MFMA causal flash attention — r9: FROZEN at r7 (proven twice). Paired grid
// dim3(16,16,2), per-iter __syncthreads, double-buffered Vp stride-35,
// K direct-from-global, swapped QK^T, P in registers (16x16x16 PV).
// NOTE: the flat-1024-grid variant of this exact body NaN'd 3x (r5/r6/r8)
// with a mechanism not yet identified — do NOT revisit without new evidence.
// ---------------------------------------------------------------------------
__global__ __launch_bounds__(256) void flash_attn_mfma(
    const unsigned short* __restrict__ qkv, unsigned short* __restrict__ Ows) {
    const int S = 2048, D3 = 3072;
    const int L = blockIdx.x + (blockIdx.y << 4) + (blockIdx.z << 8);
    const int xcd = L & 7, t = L >> 3;
    const int pp = t & 15;
    const int g2 = xcd + ((t >> 4) << 3);      // (b,h) group, constant per XCD
    const int h = g2 & 15, b = g2 >> 4;
    const int tid = threadIdx.x, wave = tid >> 6, lane = tid & 63;
    const int lro = lane & 15, grp = lane >> 4;

    __shared__ __align__(16) unsigned int Vp[2][64 * 35];  // stride 35 (bank fix)
    __shared__ float RedW[4][16][66];
    __shared__ float Lbuf[4][4][16];

    // V transpose geometry (wave-local): lane handles k-rows 2m, 2m+1 of the
    // tile (m = 8*wave + kp'), d = vo..vo+7
    const int m = tid >> 3;            // 8w + kp', wave-local col
    const int vo = (tid & 7) << 3;     // d base
    const int vcb = (wave << 3) + (grp << 1);
    const int klb = (wave << 4) + (grp << 2);   // lane's k_local base (diag mask)

    const unsigned short* kbg = qkv + (size_t)(b * S) * D3 + 1024 + h * 64;
    const unsigned short* vbg = qkv + (size_t)(b * S) * D3 + 2048 + h * 64;

    // per-lane K/V global pointers (wave's k-slice), advanced 64*D3 per tile
    const unsigned short* kfp = kbg + (size_t)(16 * wave + lro) * D3 + grp * 8;
    const unsigned short* vfp = vbg + (size_t)(2 * m) * D3 + vo;

    for (int ph = 0; ph < 2; ph++) {
        const int qt = ph ? 31 - pp : pp;
        const int q0 = qt << 6;
        const int nkt = qt + 1;

        __syncthreads();                       // prior phase fully done with Vp

        // Q frags (B-operand: col=q=lro within frag f, d-chunks grp*8 / +32)
        short8 bq[4][2];
        #pragma unroll
        for (int f = 0; f < 4; f++) {
            const unsigned short* qrow =
                qkv + (size_t)(b * S + q0 + f * 16 + lro) * D3 + h * 64 + grp * 8;
            bq[f][0] = *(const short8*)qrow;
            bq[f][1] = *(const short8*)(qrow + 32);
        }

        // prime tile 0: K frags -> regs; V -> regs -> wave-local LDS transpose
        short8 kc0 = *(const short8*)kfp;
        short8 kc1 = *(const short8*)(kfp + 32);
        {
            uint4 va = *(const uint4*)vfp;
            uint4 vb = *(const uint4*)(vfp + D3);
            const unsigned short* pa_ = (const unsigned short*)&va;
            const unsigned short* pb_ = (const unsigned short*)&vb;
            #pragma unroll
            for (int j = 0; j < 8; j++)
                Vp[0][(vo + j) * 35 + m] = (unsigned)pa_[j] | ((unsigned)pb_[j] << 16);
        }
        __syncthreads();                       // V0 visible (and orders everything)

        f32x4 acc[4][4] = {};                  // [qfrag][d-frag]
        float lsum[4] = {0.f, 0.f, 0.f, 0.f};

        for (int kt = 0; kt < nkt; kt++) {
            const int cur = kt & 1, nxt = cur ^ 1;
            const bool pf = (kt + 1 < nkt);
            short8 kn0, kn1;
            uint4 vna, vnb;
            if (pf) {                          // prefetch tile kt+1 (regs)
                const size_t off = (size_t)((kt + 1) * 64) * D3;
                kn0 = *(const short8*)(kfp + off);
                kn1 = *(const short8*)(kfp + off + 32);
                vna = *(const uint4*)(vfp + off);
                vnb = *(const uint4*)(vfp + off + D3);
            }

            // S^T = K_slice * Q^T  (swapped operands; pre-scaled so p=exp2(s))
            f32x4 s0 = {}, s1 = {}, s2 = {}, s3 = {};
            s0 = __builtin_amdgcn_mfma_f32_16x16x32_bf16(kc0, bq[0][0], s0, 0, 0, 0);
            s0 = __builtin_amdgcn_mfma_f32_16x16x32_bf16(kc1, bq[0][1], s0, 0, 0, 0);
            s1 = __builtin_amdgcn_mfma_f32_16x16x32_bf16(kc0, bq[1][0], s1, 0, 0, 0);
            s1 = __builtin_amdgcn_mfma_f32_16x16x32_bf16(kc1, bq[1][1], s1, 0, 0, 0);
            s2 = __builtin_amdgcn_mfma_f32_16x16x32_bf16(kc0, bq[2][0], s2, 0, 0, 0);
            s2 = __builtin_amdgcn_mfma_f32_16x16x32_bf16(kc1, bq[2][1], s2, 0, 0, 0);
            s3 = __builtin_amdgcn_mfma_f32_16x16x32_bf16(kc0, bq[3][0], s3, 0, 0, 0);
            s3 = __builtin_amdgcn_mfma_f32_16x16x32_bf16(kc1, bq[3][1], s3, 0, 0, 0);
            f32x4 sf[4] = {s0, s1, s2, s3};

            const bool dg = (kt == nkt - 1);
            u32x2 pw[4];
            #pragma unroll
            for (int f = 0; f < 4; f++) {
                float v0 = sf[f][0], v1 = sf[f][1], v2 = sf[f][2], v3 = sf[f][3];
                if (dg) {                      // mask k_local(klb+r) > q_local
                    int thr = (f << 4) + lro - klb;
                    if (0 > thr) v0 = -1e30f;
                    if (1 > thr) v1 = -1e30f;
                    if (2 > thr) v2 = -1e30f;
                    if (3 > thr) v3 = -1e30f;
                }
                float p0 = __builtin_amdgcn_exp2f(v0);
                float p1 = __builtin_amdgcn_exp2f(v1);
                float p2 = __builtin_amdgcn_exp2f(v2);
                float p3 = __builtin_amdgcn_exp2f(v3);
                lsum[f] += (p0 + p1) + (p2 + p3);
                unsigned u0, u1;
                asm("v_cvt_pk_bf16_f32 %0, %1, %2" : "=v"(u0) : "v"(p0), "v"(p1));
                asm("v_cvt_pk_bf16_f32 %0, %1, %2" : "=v"(u1) : "v"(p2), "v"(p3));
                pw[f][0] = u0;
                pw[f][1] = u1;
            }

            // V frags from wave-local Vp[cur] cols (two b32 reads: odd stride)
            u32x2 vv[4];
            #pragma unroll
            for (int nt = 0; nt < 4; nt++) {
                const unsigned* vr = &Vp[cur][(nt * 16 + lro) * 35 + vcb];
                vv[nt][0] = vr[0];
                vv[nt][1] = vr[1];
            }

            // O_w += P V  (P direct from registers; 16x16x16 MFMA)
            #pragma unroll
            for (int f = 0; f < 4; f++)
                #pragma unroll
                for (int nt = 0; nt < 4; nt++)
                    asm("v_mfma_f32_16x16x16_bf16 %0, %1, %2, %0"
                        : "+v"(acc[f][nt]) : "v"(pw[f]), "v"(vv[nt]));

            if (pf) {                          // wave-local transpose-write V(kt+1)
                const unsigned short* pa_ = (const unsigned short*)&vna;
                const unsigned short* pb_ = (const unsigned short*)&vnb;
                #pragma unroll
                for (int j = 0; j < 8; j++)
                    Vp[nxt][(vo + j) * 35 + m] = (unsigned)pa_[j] | ((unsigned)pb_[j] << 16);
                kc0 = kn0;
                kc1 = kn1;
            }
            __syncthreads();                   // airtight per-iter ordering (r3/r7)
        }

        // ---- epilogue: cross-wave reduce of O and lsum -------------------
        // lsum: reduce across grp lanes (same q, different k-subsets)
        #pragma unroll
        for (int f = 0; f < 4; f++) {
            lsum[f] += __shfl_xor(lsum[f], 16, 64);
            lsum[f] += __shfl_xor(lsum[f], 32, 64);
        }
        if (lane < 16) {
            #pragma unroll
            for (int f = 0; f < 4; f++) Lbuf[wave][f][lro] = lsum[f];
        }

        // O: 4 static rounds; round f: waves != f contribute acc[f] (static
        // index) to RedW[wave]; owner (wave==f) sums, normalizes, stores.
        #pragma unroll
        for (int f = 0; f < 4; f++) {
            __syncthreads();
            if (wave != f) {
                #pragma unroll
                for (int nt = 0; nt < 4; nt++)
                    #pragma unroll
                    for (int r = 0; r < 4; r++)
                        RedW[wave][(grp << 2) + r][nt * 16 + lro] = acc[f][nt][r];
            }
            __syncthreads();
            if (wave == f) {
                #pragma unroll
                for (int w2 = 0; w2 < 4; w2++) {
                    if (w2 == f) continue;     // static skip
                    #pragma unroll
                    for (int nt = 0; nt < 4; nt++)
                        #pragma unroll
                        for (int r = 0; r < 4; r++)
                            acc[f][nt][r] += RedW[w2][(grp << 2) + r][nt * 16 + lro];
                }
                #pragma unroll
                for (int r = 0; r < 4; r++) {
                    int q = (grp << 2) + r;
                    float lt = Lbuf[0][f][q] + Lbuf[1][f][q] +
                               Lbuf[2][f][q] + Lbuf[3][f][q];
                    float inv = 1.0f / lt;
                    int row = q0 + (f << 4) + q;
                    #pragma unroll
                    for (int nt = 0; nt < 4; nt++)
                        Ows[(size_t)(b * S + row) * 1024 + h * 64 + nt * 16 + lro] =
                            f2bf(acc[f][nt][r] * inv);
                }
            }
        }
    }
}

// ---------------------------------------------------------------------------
extern "C" void kernel_launch(void* const* d_in, const int* in_sizes, int n_in,
                              void* d_out, int out_size, void* d_ws, size_t ws_size,
                              hipStream_t stream) {
    const float* x    = (const float*)d_in[0];   // (2, 2048, 1024)
    const int*   pos  = (const int*)d_in[1];     // (2048,)
    const float* Wqkv = (const float*)d_in[2];   // (3072, 1024)
    const float* Wo   = (const float*)d_in[3];   // (1024, 1024)
    float* out = (float*)d_out;                  // (2, 2048, 1024) fp32

    unsigned short* xb    = (unsigned short*)d_ws;            // 4096*1024
    unsigned short* Wqkvb = xb + (size_t)4096 * 1024;         // 3072*1024
    unsigned short* Wob   = Wqkvb + (size_t)3072 * 1024;      // 1024*1024
    unsigned short* qkvb  = Wob + (size_t)1024 * 1024;        // 4096*3072
    unsigned short* Owsb  = qkvb + (size_t)4096 * 3072;       // 4096*1024

    // 0) fp32 -> bf16 (single launch)
    cvt_all_bf16<<<8192, 256, 0, stream>>>(x, Wqkv, Wo, xb, Wqkvb, Wob);

    // 1) QKV projection (M=4096, N=3072, K=1024) + fused RoPE, swizzled LDS
    gemm_nt_mfma<4, 3, true, true><<<768, 256, 0, stream>>>(
        xb, Wqkvb, qkvb, pos, 3072, 1024);

    // 2) causal flash attention (r7 frozen: paired grid, per-iter barrier)
    flash_attn_mfma<<<dim3(16, 16, 2), 256, 0, stream>>>(qkvb, Owsb);

    // 3) output projection (M=4096, N=1024, K=1024) — r9: RF=4 (BM=128),
    //    grid 256 = 32 mt x 8 nt, 1 block/CU
    gemm_nt_mfma<4, 1, false, false><<<256, 256, 0, stream>>>(
        Owsb, Wob, out, nullptr, 1024, 1024);
}

// Round 10
// 186.119 us; speedup vs baseline: 1.0035x; 1.0035x over previous
//
#include <hip/hip_runtime.h>
#include <math.h>

typedef short short8 __attribute__((ext_vector_type(8)));
typedef float f32x4 __attribute__((ext_vector_type(4)));
typedef unsigned int u32x2 __attribute__((ext_vector_type(2)));

typedef __attribute__((address_space(1))) const void* as1p;
typedef __attribute__((address_space(3))) void* as3p;

__device__ __forceinline__ unsigned short f2bf(float f) {
    unsigned int u = __float_as_uint(f);
    u += 0x7fffu + ((u >> 16) & 1u);          // RNE; inputs finite
    return (unsigned short)(u >> 16);
}

// ---------------------------------------------------------------------------
// fp32 -> bf16 conversion of x, W_qkv, W_o in one launch (4 elems/thread)
// ---------------------------------------------------------------------------
__global__ void cvt_all_bf16(const float* __restrict__ x,
                             const float* __restrict__ wqkv,
                             const float* __restrict__ wo,
                             unsigned short* __restrict__ xb,
                             unsigned short* __restrict__ wqkvb,
                             unsigned short* __restrict__ wob) {
    int i = blockIdx.x * blockDim.x + threadIdx.x;   // [0, 2097152)
    const float* src;
    unsigned short* dst;
    int off;
    if (i < 1048576)       { src = x;    dst = xb;    off = i; }
    else if (i < 1835008)  { src = wqkv; dst = wqkvb; off = i - 1048576; }
    else                   { src = wo;   dst = wob;   off = i - 1835008; }
    float4 v = ((const float4*)src)[off];
    ushort4 o = make_ushort4(f2bf(v.x), f2bf(v.y), f2bf(v.z), f2bf(v.w));
    ((ushort4*)dst)[off] = o;
}

// ---------------------------------------------------------------------------
// MFMA NT GEMM: C[m,n] = sum_k A[m,k]*B[n,k]. Block tile BM x 128 (BM=RF*32).
// r10: BK 32 -> 64. Halves the barrier count (the 2-barrier loop's
// vmcnt(0)+s_barrier drain is the structural stall in this template, ~20-25%)
// at the same total DMA count (RF+4 global_load_lds of 4 KB per step).
// Swizzle generalized to 8 chunks/row: reader physical chunk
// p = (4*kk + grp) ^ (lro&7) spreads each 8-lane phase over all 8 bank
// quads; stager source chunk = (tid&7) ^ ((tid>>3)&7) (load rows are
// multiples of 32, so the row term is load-invariant).
// 4 waves (2x2), XCD-swizzled flat grid (NTX n-tiles per XCD, B panel
// L2-resident). DO_ROPE: fused RoPE on the fp32 accumulator before store.
// gemm2 reverted to RF=2 / 512 blocks (r9's RF=4 @ 256 blocks = 1 block/CU
// cost ~7 us: TLP loss beats tile-density gain).
// ---------------------------------------------------------------------------
template <int RF, int NTX, bool BF16_OUT, bool DO_ROPE>
__global__ __launch_bounds__(256) void gemm_nt_mfma(
    const unsigned short* __restrict__ A, const unsigned short* __restrict__ B,
    void* __restrict__ Cv, const int* __restrict__ pos, int N, int K) {
    constexpr int BM = RF * 32;
    __shared__ unsigned short As[BM * 64];
    __shared__ unsigned short Bs[128 * 64];
    const int tid = threadIdx.x;
    const int wave = tid >> 6, lane = tid & 63;
    const int L = blockIdx.x;
    const int xcd = L & 7, idx = L >> 3;
    const int nt_ = xcd * NTX + idx % NTX;
    const int mt  = idx / NTX;
    const int m0 = mt * BM, n0 = nt_ << 7;
    const int wr = ((wave >> 1) & 1) * (RF * 16);
    const int wc = (wave & 1) << 6;

    // staging: load Ld covers rows 32*Ld + (tid>>3); swizzled source chunk
    const int r0 = tid >> 3;                        // 0..31
    const int ko = (((tid & 7) ^ (r0 & 7)) << 3);   // shorts
    const unsigned short* Ap[RF];
    const unsigned short* Bp[4];
    #pragma unroll
    for (int Ld = 0; Ld < RF; Ld++) Ap[Ld] = A + (size_t)(m0 + 32 * Ld + r0) * K + ko;
    #pragma unroll
    for (int Ld = 0; Ld < 4; Ld++)  Bp[Ld] = B + (size_t)(n0 + 32 * Ld + r0) * K + ko;

    f32x4 acc[RF][4] = {};
    const int lro = lane & 15;
    const int grp = lane >> 4;

    for (int k0 = 0; k0 < K; k0 += 64) {
        __syncthreads();
        #pragma unroll
        for (int Ld = 0; Ld < RF; Ld++)
            __builtin_amdgcn_global_load_lds((as1p)(Ap[Ld] + k0),
                                             (as3p)(As + (256 * Ld + tid) * 8), 16, 0, 0);
        #pragma unroll
        for (int Ld = 0; Ld < 4; Ld++)
            __builtin_amdgcn_global_load_lds((as1p)(Bp[Ld] + k0),
                                             (as3p)(Bs + (256 * Ld + tid) * 8), 16, 0, 0);
        __syncthreads();

        #pragma unroll
        for (int kk = 0; kk < 2; kk++) {
            const int c0 = ((((kk << 2) | grp) ^ (lro & 7)) << 3);  // physical chunk (shorts)
            short8 af[RF], bfr[4];
            #pragma unroll
            for (int i = 0; i < RF; i++)
                af[i] = *(const short8*)&As[(wr + i * 16 + lro) * 64 + c0];
            #pragma unroll
            for (int j = 0; j < 4; j++)
                bfr[j] = *(const short8*)&Bs[(wc + j * 16 + lro) * 64 + c0];
            #pragma unroll
            for (int i = 0; i < RF; i++)
                #pragma unroll
                for (int j = 0; j < 4; j++)
                    acc[i][j] = __builtin_amdgcn_mfma_f32_16x16x32_bf16(af[i], bfr[j], acc[i][j], 0, 0, 0);
        }
    }

    const int row_b = m0 + wr + ((lane >> 4) << 2);
    const int col_b = n0 + wc + lro;

    if constexpr (DO_ROPE) {
        const int sec = (n0 + wc) >> 10;           // 0=q, 1=k, 2=v
        if (sec < 2) {
            const float qs = (sec == 0) ? 0.18033688011112042f : 1.0f;  // 1/8*log2e
            const float sgn = (lane & 1) ? 1.0f : -1.0f;
            float ps[RF * 4];
            #pragma unroll
            for (int i = 0; i < RF; i++)
                #pragma unroll
                for (int r = 0; r < 4; r++)
                    ps[i * 4 + r] = (float)pos[(row_b + i * 16 + r) & 2047];
            #pragma unroll
            for (int j = 0; j < 4; j++) {
                float invf_rev = exp2f(-(float)((lro >> 1) + 8 * j) * 0.41524101186092029f)
                                 * 0.15915494309189535f;
                #pragma unroll
                for (int i = 0; i < RF; i++)
                    #pragma unroll
                    for (int r = 0; r < 4; r++) {
                        float rev = ps[i * 4 + r] * invf_rev;
                        rev -= floorf(rev);
                        float c = __builtin_amdgcn_cosf(rev) * qs;
                        float s = __builtin_amdgcn_sinf(rev) * (qs * sgn);
                        float mine = acc[i][j][r];
                        float partner = __shfl_xor(mine, 1, 64);
                        acc[i][j][r] = mine * c + partner * s;
                    }
            }
        }
    }

    #pragma unroll
    for (int i = 0; i < RF; i++)
        #pragma unroll
        for (int j = 0; j < 4; j++)
            #pragma unroll
            for (int r = 0; r < 4; r++) {
                size_t idx2 = (size_t)(row_b + i * 16 + r) * N + (col_b + j * 16);
                if constexpr (BF16_OUT) ((unsigned short*)Cv)[idx2] = f2bf(acc[i][j][r]);
                else ((float*)Cv)[idx2] = acc[i][j][r];
            }
}

// ---------------------------------------------------------------------------
// MFMA causal flash attention — FROZEN at r7 (proven; 44 us). Paired grid
// dim3(16,16,2), per-iter __syncthreads, double-buffered Vp stride-35,
// K direct-from-global, swapped QK^T, P in registers (16x16x16 PV).
// NOTE: the flat-1024-grid variant of this exact body NaN'd 3x (r5/r6/r8)
// with a mechanism not yet identified — do NOT revisit without new evidence.
// ---------------------------------------------------------------------------
__global__ __launch_bounds__(256) void flash_attn_mfma(
    const unsigned short* __restrict__ qkv, unsigned short* __restrict__ Ows) {
    const int S = 2048, D3 = 3072;
    const int L = blockIdx.x + (blockIdx.y << 4) + (blockIdx.z << 8);
    const int xcd = L & 7, t = L >> 3;
    const int pp = t & 15;
    const int g2 = xcd + ((t >> 4) << 3);      // (b,h) group, constant per XCD
    const int h = g2 & 15, b = g2 >> 4;
    const int tid = threadIdx.x, wave = tid >> 6, lane = tid & 63;
    const int lro = lane & 15, grp = lane >> 4;

    __shared__ __align__(16) unsigned int Vp[2][64 * 35];  // stride 35 (bank fix)
    __shared__ float RedW[4][16][66];
    __shared__ float Lbuf[4][4][16];

    // V transpose geometry (wave-local): lane handles k-rows 2m, 2m+1 of the
    // tile (m = 8*wave + kp'), d = vo..vo+7
    const int m = tid >> 3;            // 8w + kp', wave-local col
    const int vo = (tid & 7) << 3;     // d base
    const int vcb = (wave << 3) + (grp << 1);
    const int klb = (wave << 4) + (grp << 2);   // lane's k_local base (diag mask)

    const unsigned short* kbg = qkv + (size_t)(b * S) * D3 + 1024 + h * 64;
    const unsigned short* vbg = qkv + (size_t)(b * S) * D3 + 2048 + h * 64;

    // per-lane K/V global pointers (wave's k-slice), advanced 64*D3 per tile
    const unsigned short* kfp = kbg + (size_t)(16 * wave + lro) * D3 + grp * 8;
    const unsigned short* vfp = vbg + (size_t)(2 * m) * D3 + vo;

    for (int ph = 0; ph < 2; ph++) {
        const int qt = ph ? 31 - pp : pp;
        const int q0 = qt << 6;
        const int nkt = qt + 1;

        __syncthreads();                       // prior phase fully done with Vp

        // Q frags (B-operand: col=q=lro within frag f, d-chunks grp*8 / +32)
        short8 bq[4][2];
        #pragma unroll
        for (int f = 0; f < 4; f++) {
            const unsigned short* qrow =
                qkv + (size_t)(b * S + q0 + f * 16 + lro) * D3 + h * 64 + grp * 8;
            bq[f][0] = *(const short8*)qrow;
            bq[f][1] = *(const short8*)(qrow + 32);
        }

        // prime tile 0: K frags -> regs; V -> regs -> wave-local LDS transpose
        short8 kc0 = *(const short8*)kfp;
        short8 kc1 = *(const short8*)(kfp + 32);
        {
            uint4 va = *(const uint4*)vfp;
            uint4 vb = *(const uint4*)(vfp + D3);
            const unsigned short* pa_ = (const unsigned short*)&va;
            const unsigned short* pb_ = (const unsigned short*)&vb;
            #pragma unroll
            for (int j = 0; j < 8; j++)
                Vp[0][(vo + j) * 35 + m] = (unsigned)pa_[j] | ((unsigned)pb_[j] << 16);
        }
        __syncthreads();                       // V0 visible (and orders everything)

        f32x4 acc[4][4] = {};                  // [qfrag][d-frag]
        float lsum[4] = {0.f, 0.f, 0.f, 0.f};

        for (int kt = 0; kt < nkt; kt++) {
            const int cur = kt & 1, nxt = cur ^ 1;
            const bool pf = (kt + 1 < nkt);
            short8 kn0, kn1;
            uint4 vna, vnb;
            if (pf) {                          // prefetch tile kt+1 (regs)
                const size_t off = (size_t)((kt + 1) * 64) * D3;
                kn0 = *(const short8*)(kfp + off);
                kn1 = *(const short8*)(kfp + off + 32);
                vna = *(const uint4*)(vfp + off);
                vnb = *(const uint4*)(vfp + off + D3);
            }

            // S^T = K_slice * Q^T  (swapped operands; pre-scaled so p=exp2(s))
            f32x4 s0 = {}, s1 = {}, s2 = {}, s3 = {};
            s0 = __builtin_amdgcn_mfma_f32_16x16x32_bf16(kc0, bq[0][0], s0, 0, 0, 0);
            s0 = __builtin_amdgcn_mfma_f32_16x16x32_bf16(kc1, bq[0][1], s0, 0, 0, 0);
            s1 = __builtin_amdgcn_mfma_f32_16x16x32_bf16(kc0, bq[1][0], s1, 0, 0, 0);
            s1 = __builtin_amdgcn_mfma_f32_16x16x32_bf16(kc1, bq[1][1], s1, 0, 0, 0);
            s2 = __builtin_amdgcn_mfma_f32_16x16x32_bf16(kc0, bq[2][0], s2, 0, 0, 0);
            s2 = __builtin_amdgcn_mfma_f32_16x16x32_bf16(kc1, bq[2][1], s2, 0, 0, 0);
            s3 = __builtin_amdgcn_mfma_f32_16x16x32_bf16(kc0, bq[3][0], s3, 0, 0, 0);
            s3 = __builtin_amdgcn_mfma_f32_16x16x32_bf16(kc1, bq[3][1], s3, 0, 0, 0);
            f32x4 sf[4] = {s0, s1, s2, s3};

            const bool dg = (kt == nkt - 1);
            u32x2 pw[4];
            #pragma unroll
            for (int f = 0; f < 4; f++) {
                float v0 = sf[f][0], v1 = sf[f][1], v2 = sf[f][2], v3 = sf[f][3];
                if (dg) {                      // mask k_local(klb+r) > q_local
                    int thr = (f << 4) + lro - klb;
                    if (0 > thr) v0 = -1e30f;
                    if (1 > thr) v1 = -1e30f;
                    if (2 > thr) v2 = -1e30f;
                    if (3 > thr) v3 = -1e30f;
                }
                float p0 = __builtin_amdgcn_exp2f(v0);
                float p1 = __builtin_amdgcn_exp2f(v1);
                float p2 = __builtin_amdgcn_exp2f(v2);
                float p3 = __builtin_amdgcn_exp2f(v3);
                lsum[f] += (p0 + p1) + (p2 + p3);
                unsigned u0, u1;
                asm("v_cvt_pk_bf16_f32 %0, %1, %2" : "=v"(u0) : "v"(p0), "v"(p1));
                asm("v_cvt_pk_bf16_f32 %0, %1, %2" : "=v"(u1) : "v"(p2), "v"(p3));
                pw[f][0] = u0;
                pw[f][1] = u1;
            }

            // V frags from wave-local Vp[cur] cols (two b32 reads: odd stride)
            u32x2 vv[4];
            #pragma unroll
            for (int nt = 0; nt < 4; nt++) {
                const unsigned* vr = &Vp[cur][(nt * 16 + lro) * 35 + vcb];
                vv[nt][0] = vr[0];
                vv[nt][1] = vr[1];
            }

            // O_w += P V  (P direct from registers; 16x16x16 MFMA)
            #pragma unroll
            for (int f = 0; f < 4; f++)
                #pragma unroll
                for (int nt = 0; nt < 4; nt++)
                    asm("v_mfma_f32_16x16x16_bf16 %0, %1, %2, %0"
                        : "+v"(acc[f][nt]) : "v"(pw[f]), "v"(vv[nt]));

            if (pf) {                          // wave-local transpose-write V(kt+1)
                const unsigned short* pa_ = (const unsigned short*)&vna;
                const unsigned short* pb_ = (const unsigned short*)&vnb;
                #pragma unroll
                for (int j = 0; j < 8; j++)
                    Vp[nxt][(vo + j) * 35 + m] = (unsigned)pa_[j] | ((unsigned)pb_[j] << 16);
                kc0 = kn0;
                kc1 = kn1;
            }
            __syncthreads();                   // airtight per-iter ordering (r3/r7)
        }

        // ---- epilogue: cross-wave reduce of O and lsum -------------------
        // lsum: reduce across grp lanes (same q, different k-subsets)
        #pragma unroll
        for (int f = 0; f < 4; f++) {
            lsum[f] += __shfl_xor(lsum[f], 16, 64);
            lsum[f] += __shfl_xor(lsum[f], 32, 64);
        }
        if (lane < 16) {
            #pragma unroll
            for (int f = 0; f < 4; f++) Lbuf[wave][f][lro] = lsum[f];
        }

        // O: 4 static rounds; round f: waves != f contribute acc[f] (static
        // index) to RedW[wave]; owner (wave==f) sums, normalizes, stores.
        #pragma unroll
        for (int f = 0; f < 4; f++) {
            __syncthreads();
            if (wave != f) {
                #pragma unroll
                for (int nt = 0; nt < 4; nt++)
                    #pragma unroll
                    for (int r = 0; r < 4; r++)
                        RedW[wave][(grp << 2) + r][nt * 16 + lro] = acc[f][nt][r];
            }
            __syncthreads();
            if (wave == f) {
                #pragma unroll
                for (int w2 = 0; w2 < 4; w2++) {
                    if (w2 == f) continue;     // static skip
                    #pragma unroll
                    for (int nt = 0; nt < 4; nt++)
                        #pragma unroll
                        for (int r = 0; r < 4; r++)
                            acc[f][nt][r] += RedW[w2][(grp << 2) + r][nt * 16 + lro];
                }
                #pragma unroll
                for (int r = 0; r < 4; r++) {
                    int q = (grp << 2) + r;
                    float lt = Lbuf[0][f][q] + Lbuf[1][f][q] +
                               Lbuf[2][f][q] + Lbuf[3][f][q];
                    float inv = 1.0f / lt;
                    int row = q0 + (f << 4) + q;
                    #pragma unroll
                    for (int nt = 0; nt < 4; nt++)
                        Ows[(size_t)(b * S + row) * 1024 + h * 64 + nt * 16 + lro] =
                            f2bf(acc[f][nt][r] * inv);
                }
            }
        }
    }
}

// ---------------------------------------------------------------------------
extern "C" void kernel_launch(void* const* d_in, const int* in_sizes, int n_in,
                              void* d_out, int out_size, void* d_ws, size_t ws_size,
                              hipStream_t stream) {
    const float* x    = (const float*)d_in[0];   // (2, 2048, 1024)
    const int*   pos  = (const int*)d_in[1];     // (2048,)
    const float* Wqkv = (const float*)d_in[2];   // (3072, 1024)
    const float* Wo   = (const float*)d_in[3];   // (1024, 1024)
    float* out = (float*)d_out;                  // (2, 2048, 1024) fp32

    unsigned short* xb    = (unsigned short*)d_ws;            // 4096*1024
    unsigned short* Wqkvb = xb + (size_t)4096 * 1024;         // 3072*1024
    unsigned short* Wob   = Wqkvb + (size_t)3072 * 1024;      // 1024*1024
    unsigned short* qkvb  = Wob + (size_t)1024 * 1024;        // 4096*3072
    unsigned short* Owsb  = qkvb + (size_t)4096 * 3072;       // 4096*1024

    // 0) fp32 -> bf16 (single launch)
    cvt_all_bf16<<<8192, 256, 0, stream>>>(x, Wqkv, Wo, xb, Wqkvb, Wob);

    // 1) QKV projection (M=4096, N=3072, K=1024) + fused RoPE, BK=64
    gemm_nt_mfma<4, 3, true, true><<<768, 256, 0, stream>>>(
        xb, Wqkvb, qkvb, pos, 3072, 1024);

    // 2) causal flash attention (r7 frozen: paired grid, per-iter barrier)
    flash_attn_mfma<<<dim3(16, 16, 2), 256, 0, stream>>>(qkvb, Owsb);

    // 3) output projection (M=4096, N=1024, K=1024) — RF=2 / 512 blocks
    //    (reverted from r9's 256-block RF=4: 1 block/CU lost ~7 us), BK=64
    gemm_nt_mfma<2, 1, false, false><<<512, 256, 0, stream>>>(
        Owsb, Wob, out, nullptr, 1024, 1024);
}

// Round 11
// 180.031 us; speedup vs baseline: 1.0375x; 1.0338x over previous
//
#include <hip/hip_runtime.h>
#include <math.h>

typedef short short8 __attribute__((ext_vector_type(8)));
typedef float f32x4 __attribute__((ext_vector_type(4)));
typedef unsigned int u32x2 __attribute__((ext_vector_type(2)));

typedef __attribute__((address_space(1))) const void* as1p;
typedef __attribute__((address_space(3))) void* as3p;

__device__ __forceinline__ unsigned short f2bf(float f) {
    unsigned int u = __float_as_uint(f);
    u += 0x7fffu + ((u >> 16) & 1u);          // RNE; inputs finite
    return (unsigned short)(u >> 16);
}

// ---------------------------------------------------------------------------
// fp32 -> bf16 conversion of x, W_qkv, W_o in one launch (4 elems/thread)
// ---------------------------------------------------------------------------
__global__ void cvt_all_bf16(const float* __restrict__ x,
                             const float* __restrict__ wqkv,
                             const float* __restrict__ wo,
                             unsigned short* __restrict__ xb,
                             unsigned short* __restrict__ wqkvb,
                             unsigned short* __restrict__ wob) {
    int i = blockIdx.x * blockDim.x + threadIdx.x;   // [0, 2097152)
    const float* src;
    unsigned short* dst;
    int off;
    if (i < 1048576)       { src = x;    dst = xb;    off = i; }
    else if (i < 1835008)  { src = wqkv; dst = wqkvb; off = i - 1048576; }
    else                   { src = wo;   dst = wob;   off = i - 1835008; }
    float4 v = ((const float4*)src)[off];
    ushort4 o = make_ushort4(f2bf(v.x), f2bf(v.y), f2bf(v.z), f2bf(v.w));
    ((ushort4*)dst)[off] = o;
}

// ---------------------------------------------------------------------------
// MFMA NT GEMM: C[m,n] = sum_k A[m,k]*B[n,k]. Block tile BM x 128 (BM=RF*32),
// BK=32, 4 waves (2x2), global_load_lds width-16 staging, 2-barrier K-loop.
// BK=32 is the measured optimum for this template: r10's BK=64 regressed
// gemm1 43->51.6 us (matches learn_hip m132: bigger K-steps lose in the
// 2-barrier structure — fewer but larger vmcnt(0)+barrier drains).
// LDS bank-conflict fix via global-source XOR swizzle. XCD-swizzled flat
// grid. DO_ROPE: fused RoPE on the fp32 accumulator before store.
// ---------------------------------------------------------------------------
template <int RF, int NTX, bool BF16_OUT, bool DO_ROPE>
__global__ __launch_bounds__(256) void gemm_nt_mfma(
    const unsigned short* __restrict__ A, const unsigned short* __restrict__ B,
    void* __restrict__ Cv, const int* __restrict__ pos, int N, int K) {
    constexpr int BM = RF * 32;
    __shared__ unsigned short As[BM * 32];
    __shared__ unsigned short Bs[128 * 32];
    const int tid = threadIdx.x;
    const int wave = tid >> 6, lane = tid & 63;
    const int L = blockIdx.x;
    const int xcd = L & 7, idx = L >> 3;
    const int nt_ = xcd * NTX + idx % NTX;
    const int mt  = idx / NTX;
    const int m0 = mt * BM, n0 = nt_ << 7;
    const int wr = ((wave >> 1) & 1) * (RF * 16);
    const int wc = (wave & 1) << 6;

    const int r0 = tid >> 2;
    const int ko = (((tid & 3) ^ ((r0 >> 1) & 3)) << 3);
    const unsigned short* Ap0 = A + (size_t)(m0 + r0) * K + ko;
    const unsigned short* Ap1 = A + (size_t)(m0 + (RF == 4 ? 64 : 0) + r0) * K + ko;
    const unsigned short* Bp0 = B + (size_t)(n0 + r0) * K + ko;
    const unsigned short* Bp1 = B + (size_t)(n0 + 64 + r0) * K + ko;

    f32x4 acc[RF][4] = {};
    const int lro = lane & 15;
    const int cs = ((lane >> 4) ^ ((lro >> 1) & 3)) << 3;  // physical chunk (shorts)

    for (int k0 = 0; k0 < K; k0 += 32) {
        __syncthreads();
        __builtin_amdgcn_global_load_lds((as1p)(Ap0 + k0), (as3p)(As + tid * 8), 16, 0, 0);
        if constexpr (RF == 4)
            __builtin_amdgcn_global_load_lds((as1p)(Ap1 + k0), (as3p)(As + (256 + tid) * 8), 16, 0, 0);
        __builtin_amdgcn_global_load_lds((as1p)(Bp0 + k0), (as3p)(Bs + tid * 8), 16, 0, 0);
        __builtin_amdgcn_global_load_lds((as1p)(Bp1 + k0), (as3p)(Bs + (256 + tid) * 8), 16, 0, 0);
        __syncthreads();

        short8 af[RF], bfr[4];
        #pragma unroll
        for (int i = 0; i < RF; i++) af[i] = *(const short8*)&As[(wr + i * 16 + lro) * 32 + cs];
        #pragma unroll
        for (int j = 0; j < 4; j++) bfr[j] = *(const short8*)&Bs[(wc + j * 16 + lro) * 32 + cs];
        #pragma unroll
        for (int i = 0; i < RF; i++)
            #pragma unroll
            for (int j = 0; j < 4; j++)
                acc[i][j] = __builtin_amdgcn_mfma_f32_16x16x32_bf16(af[i], bfr[j], acc[i][j], 0, 0, 0);
    }

    const int row_b = m0 + wr + ((lane >> 4) << 2);
    const int col_b = n0 + wc + lro;

    if constexpr (DO_ROPE) {
        const int sec = (n0 + wc) >> 10;           // 0=q, 1=k, 2=v
        if (sec < 2) {
            const float qs = (sec == 0) ? 0.18033688011112042f : 1.0f;  // 1/8*log2e
            const float sgn = (lane & 1) ? 1.0f : -1.0f;
            float ps[RF * 4];
            #pragma unroll
            for (int i = 0; i < RF; i++)
                #pragma unroll
                for (int r = 0; r < 4; r++)
                    ps[i * 4 + r] = (float)pos[(row_b + i * 16 + r) & 2047];
            #pragma unroll
            for (int j = 0; j < 4; j++) {
                float invf_rev = exp2f(-(float)((lro >> 1) + 8 * j) * 0.41524101186092029f)
                                 * 0.15915494309189535f;
                #pragma unroll
                for (int i = 0; i < RF; i++)
                    #pragma unroll
                    for (int r = 0; r < 4; r++) {
                        float rev = ps[i * 4 + r] * invf_rev;
                        rev -= floorf(rev);
                        float c = __builtin_amdgcn_cosf(rev) * qs;
                        float s = __builtin_amdgcn_sinf(rev) * (qs * sgn);
                        float mine = acc[i][j][r];
                        float partner = __shfl_xor(mine, 1, 64);
                        acc[i][j][r] = mine * c + partner * s;
                    }
            }
        }
    }

    #pragma unroll
    for (int i = 0; i < RF; i++)
        #pragma unroll
        for (int j = 0; j < 4; j++)
            #pragma unroll
            for (int r = 0; r < 4; r++) {
                size_t idx2 = (size_t)(row_b + i * 16 + r) * N + (col_b + j * 16);
                if constexpr (BF16_OUT) ((unsigned short*)Cv)[idx2] = f2bf(acc[i][j][r]);
                else ((float*)Cv)[idx2] = acc[i][j][r];
            }
}

// ---------------------------------------------------------------------------
// MFMA causal flash attention — FROZEN at r7 (proven twice at 44 us). Paired
// grid dim3(16,16,2), per-iter __syncthreads, double-buffered Vp stride-35,
// K direct-from-global, swapped QK^T, P in registers (16x16x16 PV).
// NOTE: the flat-1024-grid variant of this exact body NaN'd 3x (r5/r6/r8)
// with a mechanism not yet identified — do NOT revisit without new evidence.
// ---------------------------------------------------------------------------
__global__ __launch_bounds__(256) void flash_attn_mfma(
    const unsigned short* __restrict__ qkv, unsigned short* __restrict__ Ows) {
    const int S = 2048, D3 = 3072;
    const int L = blockIdx.x + (blockIdx.y << 4) + (blockIdx.z << 8);
    const int xcd = L & 7, t = L >> 3;
    const int pp = t & 15;
    const int g2 = xcd + ((t >> 4) << 3);      // (b,h) group, constant per XCD
    const int h = g2 & 15, b = g2 >> 4;
    const int tid = threadIdx.x, wave = tid >> 6, lane = tid & 63;
    const int lro = lane & 15, grp = lane >> 4;

    __shared__ __align__(16) unsigned int Vp[2][64 * 35];  // stride 35 (bank fix)
    __shared__ float RedW[4][16][66];
    __shared__ float Lbuf[4][4][16];

    // V transpose geometry (wave-local): lane handles k-rows 2m, 2m+1 of the
    // tile (m = 8*wave + kp'), d = vo..vo+7
    const int m = tid >> 3;            // 8w + kp', wave-local col
    const int vo = (tid & 7) << 3;     // d base
    const int vcb = (wave << 3) + (grp << 1);
    const int klb = (wave << 4) + (grp << 2);   // lane's k_local base (diag mask)

    const unsigned short* kbg = qkv + (size_t)(b * S) * D3 + 1024 + h * 64;
    const unsigned short* vbg = qkv + (size_t)(b * S) * D3 + 2048 + h * 64;

    // per-lane K/V global pointers (wave's k-slice), advanced 64*D3 per tile
    const unsigned short* kfp = kbg + (size_t)(16 * wave + lro) * D3 + grp * 8;
    const unsigned short* vfp = vbg + (size_t)(2 * m) * D3 + vo;

    for (int ph = 0; ph < 2; ph++) {
        const int qt = ph ? 31 - pp : pp;
        const int q0 = qt << 6;
        const int nkt = qt + 1;

        __syncthreads();                       // prior phase fully done with Vp

        // Q frags (B-operand: col=q=lro within frag f, d-chunks grp*8 / +32)
        short8 bq[4][2];
        #pragma unroll
        for (int f = 0; f < 4; f++) {
            const unsigned short* qrow =
                qkv + (size_t)(b * S + q0 + f * 16 + lro) * D3 + h * 64 + grp * 8;
            bq[f][0] = *(const short8*)qrow;
            bq[f][1] = *(const short8*)(qrow + 32);
        }

        // prime tile 0: K frags -> regs; V -> regs -> wave-local LDS transpose
        short8 kc0 = *(const short8*)kfp;
        short8 kc1 = *(const short8*)(kfp + 32);
        {
            uint4 va = *(const uint4*)vfp;
            uint4 vb = *(const uint4*)(vfp + D3);
            const unsigned short* pa_ = (const unsigned short*)&va;
            const unsigned short* pb_ = (const unsigned short*)&vb;
            #pragma unroll
            for (int j = 0; j < 8; j++)
                Vp[0][(vo + j) * 35 + m] = (unsigned)pa_[j] | ((unsigned)pb_[j] << 16);
        }
        __syncthreads();                       // V0 visible (and orders everything)

        f32x4 acc[4][4] = {};                  // [qfrag][d-frag]
        float lsum[4] = {0.f, 0.f, 0.f, 0.f};

        for (int kt = 0; kt < nkt; kt++) {
            const int cur = kt & 1, nxt = cur ^ 1;
            const bool pf = (kt + 1 < nkt);
            short8 kn0, kn1;
            uint4 vna, vnb;
            if (pf) {                          // prefetch tile kt+1 (regs)
                const size_t off = (size_t)((kt + 1) * 64) * D3;
                kn0 = *(const short8*)(kfp + off);
                kn1 = *(const short8*)(kfp + off + 32);
                vna = *(const uint4*)(vfp + off);
                vnb = *(const uint4*)(vfp + off + D3);
            }

            // S^T = K_slice * Q^T  (swapped operands; pre-scaled so p=exp2(s))
            f32x4 s0 = {}, s1 = {}, s2 = {}, s3 = {};
            s0 = __builtin_amdgcn_mfma_f32_16x16x32_bf16(kc0, bq[0][0], s0, 0, 0, 0);
            s0 = __builtin_amdgcn_mfma_f32_16x16x32_bf16(kc1, bq[0][1], s0, 0, 0, 0);
            s1 = __builtin_amdgcn_mfma_f32_16x16x32_bf16(kc0, bq[1][0], s1, 0, 0, 0);
            s1 = __builtin_amdgcn_mfma_f32_16x16x32_bf16(kc1, bq[1][1], s1, 0, 0, 0);
            s2 = __builtin_amdgcn_mfma_f32_16x16x32_bf16(kc0, bq[2][0], s2, 0, 0, 0);
            s2 = __builtin_amdgcn_mfma_f32_16x16x32_bf16(kc1, bq[2][1], s2, 0, 0, 0);
            s3 = __builtin_amdgcn_mfma_f32_16x16x32_bf16(kc0, bq[3][0], s3, 0, 0, 0);
            s3 = __builtin_amdgcn_mfma_f32_16x16x32_bf16(kc1, bq[3][1], s3, 0, 0, 0);
            f32x4 sf[4] = {s0, s1, s2, s3};

            const bool dg = (kt == nkt - 1);
            u32x2 pw[4];
            #pragma unroll
            for (int f = 0; f < 4; f++) {
                float v0 = sf[f][0], v1 = sf[f][1], v2 = sf[f][2], v3 = sf[f][3];
                if (dg) {                      // mask k_local(klb+r) > q_local
                    int thr = (f << 4) + lro - klb;
                    if (0 > thr) v0 = -1e30f;
                    if (1 > thr) v1 = -1e30f;
                    if (2 > thr) v2 = -1e30f;
                    if (3 > thr) v3 = -1e30f;
                }
                float p0 = __builtin_amdgcn_exp2f(v0);
                float p1 = __builtin_amdgcn_exp2f(v1);
                float p2 = __builtin_amdgcn_exp2f(v2);
                float p3 = __builtin_amdgcn_exp2f(v3);
                lsum[f] += (p0 + p1) + (p2 + p3);
                unsigned u0, u1;
                asm("v_cvt_pk_bf16_f32 %0, %1, %2" : "=v"(u0) : "v"(p0), "v"(p1));
                asm("v_cvt_pk_bf16_f32 %0, %1, %2" : "=v"(u1) : "v"(p2), "v"(p3));
                pw[f][0] = u0;
                pw[f][1] = u1;
            }

            // V frags from wave-local Vp[cur] cols (two b32 reads: odd stride)
            u32x2 vv[4];
            #pragma unroll
            for (int nt = 0; nt < 4; nt++) {
                const unsigned* vr = &Vp[cur][(nt * 16 + lro) * 35 + vcb];
                vv[nt][0] = vr[0];
                vv[nt][1] = vr[1];
            }

            // O_w += P V  (P direct from registers; 16x16x16 MFMA)
            #pragma unroll
            for (int f = 0; f < 4; f++)
                #pragma unroll
                for (int nt = 0; nt < 4; nt++)
                    asm("v_mfma_f32_16x16x16_bf16 %0, %1, %2, %0"
                        : "+v"(acc[f][nt]) : "v"(pw[f]), "v"(vv[nt]));

            if (pf) {                          // wave-local transpose-write V(kt+1)
                const unsigned short* pa_ = (const unsigned short*)&vna;
                const unsigned short* pb_ = (const unsigned short*)&vnb;
                #pragma unroll
                for (int j = 0; j < 8; j++)
                    Vp[nxt][(vo + j) * 35 + m] = (unsigned)pa_[j] | ((unsigned)pb_[j] << 16);
                kc0 = kn0;
                kc1 = kn1;
            }
            __syncthreads();                   // airtight per-iter ordering (r3/r7)
        }

        // ---- epilogue: cross-wave reduce of O and lsum -------------------
        // lsum: reduce across grp lanes (same q, different k-subsets)
        #pragma unroll
        for (int f = 0; f < 4; f++) {
            lsum[f] += __shfl_xor(lsum[f], 16, 64);
            lsum[f] += __shfl_xor(lsum[f], 32, 64);
        }
        if (lane < 16) {
            #pragma unroll
            for (int f = 0; f < 4; f++) Lbuf[wave][f][lro] = lsum[f];
        }

        // O: 4 static rounds; round f: waves != f contribute acc[f] (static
        // index) to RedW[wave]; owner (wave==f) sums, normalizes, stores.
        #pragma unroll
        for (int f = 0; f < 4; f++) {
            __syncthreads();
            if (wave != f) {
                #pragma unroll
                for (int nt = 0; nt < 4; nt++)
                    #pragma unroll
                    for (int r = 0; r < 4; r++)
                        RedW[wave][(grp << 2) + r][nt * 16 + lro] = acc[f][nt][r];
            }
            __syncthreads();
            if (wave == f) {
                #pragma unroll
                for (int w2 = 0; w2 < 4; w2++) {
                    if (w2 == f) continue;     // static skip
                    #pragma unroll
                    for (int nt = 0; nt < 4; nt++)
                        #pragma unroll
                        for (int r = 0; r < 4; r++)
                            acc[f][nt][r] += RedW[w2][(grp << 2) + r][nt * 16 + lro];
                }
                #pragma unroll
                for (int r = 0; r < 4; r++) {
                    int q = (grp << 2) + r;
                    float lt = Lbuf[0][f][q] + Lbuf[1][f][q] +
                               Lbuf[2][f][q] + Lbuf[3][f][q];
                    float inv = 1.0f / lt;
                    int row = q0 + (f << 4) + q;
                    #pragma unroll
                    for (int nt = 0; nt < 4; nt++)
                        Ows[(size_t)(b * S + row) * 1024 + h * 64 + nt * 16 + lro] =
                            f2bf(acc[f][nt][r] * inv);
                }
            }
        }
    }
}

// ---------------------------------------------------------------------------
extern "C" void kernel_launch(void* const* d_in, const int* in_sizes, int n_in,
                              void* d_out, int out_size, void* d_ws, size_t ws_size,
                              hipStream_t stream) {
    const float* x    = (const float*)d_in[0];   // (2, 2048, 1024)
    const int*   pos  = (const int*)d_in[1];     // (2048,)
    const float* Wqkv = (const float*)d_in[2];   // (3072, 1024)
    const float* Wo   = (const float*)d_in[3];   // (1024, 1024)
    float* out = (float*)d_out;                  // (2, 2048, 1024) fp32

    unsigned short* xb    = (unsigned short*)d_ws;            // 4096*1024
    unsigned short* Wqkvb = xb + (size_t)4096 * 1024;         // 3072*1024
    unsigned short* Wob   = Wqkvb + (size_t)3072 * 1024;      // 1024*1024
    unsigned short* qkvb  = Wob + (size_t)1024 * 1024;        // 4096*3072
    unsigned short* Owsb  = qkvb + (size_t)4096 * 3072;       // 4096*1024

    // 0) fp32 -> bf16 (single launch)
    cvt_all_bf16<<<8192, 256, 0, stream>>>(x, Wqkv, Wo, xb, Wqkvb, Wob);

    // 1) QKV projection (M=4096, N=3072, K=1024) + fused RoPE, BK=32
    gemm_nt_mfma<4, 3, true, true><<<768, 256, 0, stream>>>(
        xb, Wqkvb, qkvb, pos, 3072, 1024);

    // 2) causal flash attention (r7 frozen: paired grid, per-iter barrier)
    flash_attn_mfma<<<dim3(16, 16, 2), 256, 0, stream>>>(qkvb, Owsb);

    // 3) output projection (M=4096, N=1024, K=1024), RF=2 / 512 blocks, BK=32
    gemm_nt_mfma<2, 1, false, false><<<512, 256, 0, stream>>>(
        Owsb, Wob, out, nullptr, 1024, 1024);
}